// Round 1
// baseline (389.453 us; speedup 1.0000x reference)
//
#include <hip/hip_runtime.h>

typedef unsigned short u16;
typedef unsigned int u32;
typedef __attribute__((ext_vector_type(8))) short bf16x8;
typedef __attribute__((ext_vector_type(4))) float f32x4;
typedef __attribute__((ext_vector_type(4))) unsigned short u16x4;

__device__ __forceinline__ u16 f2b(float f) {
  u32 u = __builtin_bit_cast(u32, f);
  u32 r = (u + 0x7FFFu + ((u >> 16) & 1u)) >> 16;  // RNE
  return (u16)r;
}

__device__ __forceinline__ f32x4 mfma16(bf16x8 a, bf16x8 b, f32x4 c) {
  return __builtin_amdgcn_mfma_f32_16x16x32_bf16(a, b, c, 0, 0, 0);
}

// ---------------- kernel 0: fp32 -> bf16 conversion (Wq pre-scaled 1/8) ----
// segments in vec8 units: x 262144 | wq 32768 | wk 32768 | wv 32768 | wo 4096
__global__ __launch_bounds__(256) void cvt_kernel(
    const float* __restrict__ x, const float* __restrict__ wq,
    const float* __restrict__ wk, const float* __restrict__ wv,
    const float* __restrict__ wo,
    u16* __restrict__ xb, u16* __restrict__ wqb, u16* __restrict__ wkb,
    u16* __restrict__ wvb, u16* __restrict__ wob) {
  int i = blockIdx.x * 256 + threadIdx.x;
  const float* src; u16* dst; int off; float scale = 1.0f;
  if (i < 262144)      { src = x;  dst = xb;  off = i; }
  else if (i < 294912) { src = wq; dst = wqb; off = i - 262144; scale = 0.125f; }
  else if (i < 327680) { src = wk; dst = wkb; off = i - 294912; }
  else if (i < 360448) { src = wv; dst = wvb; off = i - 327680; }
  else                 { src = wo; dst = wob; off = i - 360448; }
  const float4* s4 = (const float4*)src;
  float4 a = s4[off * 2], b = s4[off * 2 + 1];
  u16x4 r0, r1;
  r0.x = f2b(a.x * scale); r0.y = f2b(a.y * scale);
  r0.z = f2b(a.z * scale); r0.w = f2b(a.w * scale);
  r1.x = f2b(b.x * scale); r1.y = f2b(b.y * scale);
  r1.z = f2b(b.z * scale); r1.w = f2b(b.w * scale);
  ((u16x4*)dst)[off * 2] = r0;
  ((u16x4*)dst)[off * 2 + 1] = r1;
}

// ---------------- kernel 1: QKV projection  Y = xb @ W^T -------------------
// grid (64 row-tiles, 8 col-tiles(=head), 3 weights), 256 thr (4 waves).
// Each wave: 16 rows x 64 cols. Q,K -> [h][n][64]; V -> transposed [h][64][n].
__global__ __launch_bounds__(256) void qkv_kernel(
    const u16* __restrict__ xb, const u16* __restrict__ wqb,
    const u16* __restrict__ wkb, const u16* __restrict__ wvb,
    u16* __restrict__ Qg, u16* __restrict__ Kg, u16* __restrict__ Vt) {
  int wave = threadIdx.x >> 6, lane = threadIdx.x & 63;
  int lr = lane & 15, lg = lane >> 4;
  int row0 = blockIdx.x * 64 + wave * 16;
  int h = blockIdx.y;
  int col0 = h * 64;
  int mode = blockIdx.z;
  const u16* W = (mode == 0) ? wqb : (mode == 1) ? wkb : wvb;
  f32x4 acc[4] = {{0,0,0,0},{0,0,0,0},{0,0,0,0},{0,0,0,0}};
  const u16* arow = xb + (size_t)(row0 + lr) * 512;
#pragma unroll 4
  for (int kk = 0; kk < 16; ++kk) {
    bf16x8 aF = *(const bf16x8*)(arow + kk * 32 + lg * 8);
#pragma unroll
    for (int ni = 0; ni < 4; ++ni) {
      bf16x8 bF = *(const bf16x8*)(W + (size_t)(col0 + ni * 16 + lr) * 512 + kk * 32 + lg * 8);
      acc[ni] = mfma16(aF, bF, acc[ni]);
    }
  }
#pragma unroll
  for (int ni = 0; ni < 4; ++ni)
#pragma unroll
    for (int r = 0; r < 4; ++r) {
      int row = row0 + lg * 4 + r;
      int d = ni * 16 + lr;
      u16 v = f2b(acc[ni][r]);
      if (mode == 0)      Qg[((size_t)h * 4096 + row) * 64 + d] = v;
      else if (mode == 1) Kg[((size_t)h * 4096 + row) * 64 + d] = v;
      else                Vt[((size_t)h * 64 + d) * 4096 + row] = v;
    }
}

// ---------------- kernel 2: flash attention --------------------------------
// grid (64 q-tiles, 8 heads), 256 thr (4 waves), 16 q-rows/wave, KV-tile 64.
__global__ __launch_bounds__(256) void attn_kernel(
    const u16* __restrict__ Qg, const u16* __restrict__ Kg,
    const u16* __restrict__ Vt, u16* __restrict__ Hg) {
  __shared__ __align__(16) u16 plds[4][16][64];
  int wave = threadIdx.x >> 6, lane = threadIdx.x & 63;
  int lr = lane & 15, lg = lane >> 4;
  int h = blockIdx.y;
  int n0 = blockIdx.x * 64 + wave * 16;
  const u16* Qh = Qg + (size_t)h * 4096 * 64;
  const u16* Kh = Kg + (size_t)h * 4096 * 64;
  const u16* Vh = Vt + (size_t)h * 64 * 4096;

  bf16x8 qF0 = *(const bf16x8*)(Qh + (size_t)(n0 + lr) * 64 + lg * 8);
  bf16x8 qF1 = *(const bf16x8*)(Qh + (size_t)(n0 + lr) * 64 + 32 + lg * 8);

  float m_r[4], l_r[4];
  f32x4 acc_o[4] = {{0,0,0,0},{0,0,0,0},{0,0,0,0},{0,0,0,0}};
#pragma unroll
  for (int r = 0; r < 4; ++r) { m_r[r] = -1e30f; l_r[r] = 0.0f; }

  for (int mt = 0; mt < 64; ++mt) {
    int m0 = mt * 64;
    f32x4 s[4] = {{0,0,0,0},{0,0,0,0},{0,0,0,0},{0,0,0,0}};
#pragma unroll
    for (int nt = 0; nt < 4; ++nt) {
      const u16* krow = Kh + (size_t)(m0 + nt * 16 + lr) * 64;
      s[nt] = mfma16(qF0, *(const bf16x8*)(krow + lg * 8), s[nt]);
      s[nt] = mfma16(qF1, *(const bf16x8*)(krow + 32 + lg * 8), s[nt]);
    }
    float nm[4], sc[4], ps[4];
#pragma unroll
    for (int r = 0; r < 4; ++r) {
      float mx = fmaxf(fmaxf(s[0][r], s[1][r]), fmaxf(s[2][r], s[3][r]));
#pragma unroll
      for (int off = 1; off < 16; off <<= 1) mx = fmaxf(mx, __shfl_xor(mx, off));
      nm[r] = fmaxf(m_r[r], mx);
      sc[r] = __expf(m_r[r] - nm[r]);
      ps[r] = 0.0f;
    }
#pragma unroll
    for (int nt = 0; nt < 4; ++nt)
#pragma unroll
      for (int r = 0; r < 4; ++r) {
        float p = __expf(s[nt][r] - nm[r]);
        ps[r] += p;
        plds[wave][lg * 4 + r][nt * 16 + lr] = f2b(p);
      }
#pragma unroll
    for (int r = 0; r < 4; ++r) {
      float su = ps[r];
#pragma unroll
      for (int off = 1; off < 16; off <<= 1) su += __shfl_xor(su, off);
      l_r[r] = l_r[r] * sc[r] + su;
      m_r[r] = nm[r];
#pragma unroll
      for (int dt = 0; dt < 4; ++dt) acc_o[dt][r] *= sc[r];
    }
    __syncthreads();
    bf16x8 pa0 = *(const bf16x8*)(&plds[wave][lr][lg * 8]);
    bf16x8 pa1 = *(const bf16x8*)(&plds[wave][lr][32 + lg * 8]);
#pragma unroll
    for (int dt = 0; dt < 4; ++dt) {
      const u16* vrow = Vh + (size_t)(dt * 16 + lr) * 4096 + m0;
      acc_o[dt] = mfma16(pa0, *(const bf16x8*)(vrow + lg * 8), acc_o[dt]);
      acc_o[dt] = mfma16(pa1, *(const bf16x8*)(vrow + 32 + lg * 8), acc_o[dt]);
    }
    __syncthreads();
  }
#pragma unroll
  for (int dt = 0; dt < 4; ++dt)
#pragma unroll
    for (int r = 0; r < 4; ++r) {
      float o = acc_o[dt][r] / l_r[r];
      int row = n0 + lg * 4 + r;
      Hg[(size_t)row * 512 + h * 64 + dt * 16 + lr] = f2b(o);
    }
}

// ---------------- kernel 3: out = H @ Wo^T + bo  (fp32 out) ----------------
__global__ __launch_bounds__(256) void proj_kernel(
    const u16* __restrict__ Hg, const u16* __restrict__ wob,
    const float* __restrict__ bo, float* __restrict__ out) {
  int wave = threadIdx.x >> 6, lane = threadIdx.x & 63;
  int lr = lane & 15, lg = lane >> 4;
  int row0 = blockIdx.x * 64 + wave * 16;
  f32x4 acc[4] = {{0,0,0,0},{0,0,0,0},{0,0,0,0},{0,0,0,0}};
  const u16* arow = Hg + (size_t)(row0 + lr) * 512;
#pragma unroll 4
  for (int kk = 0; kk < 16; ++kk) {
    bf16x8 aF = *(const bf16x8*)(arow + kk * 32 + lg * 8);
#pragma unroll
    for (int ni = 0; ni < 4; ++ni) {
      bf16x8 bF = *(const bf16x8*)(wob + (size_t)(ni * 16 + lr) * 512 + kk * 32 + lg * 8);
      acc[ni] = mfma16(aF, bF, acc[ni]);
    }
  }
#pragma unroll
  for (int ni = 0; ni < 4; ++ni)
#pragma unroll
    for (int r = 0; r < 4; ++r) {
      int row = row0 + lg * 4 + r;
      int col = ni * 16 + lr;
      out[(size_t)row * 64 + col] = acc[ni][r] + bo[col];
    }
}

extern "C" void kernel_launch(void* const* d_in, const int* in_sizes, int n_in,
                              void* d_out, int out_size, void* d_ws, size_t ws_size,
                              hipStream_t stream) {
  const float* x  = (const float*)d_in[0];
  const float* Wq = (const float*)d_in[1];
  const float* Wk = (const float*)d_in[2];
  const float* Wv = (const float*)d_in[3];
  const float* Wo = (const float*)d_in[4];
  const float* bo = (const float*)d_in[5];
  float* out = (float*)d_out;

  u16* xb  = (u16*)d_ws;             // 4096*512
  u16* wqb = xb + 4096 * 512;        // 512*512
  u16* wkb = wqb + 512 * 512;
  u16* wvb = wkb + 512 * 512;
  u16* wob = wvb + 512 * 512;        // 64*512
  u16* Qg  = wob + 64 * 512;         // 8*4096*64
  u16* Kg  = Qg + 8 * 4096 * 64;
  u16* Vt  = Kg + 8 * 4096 * 64;
  u16* Hg  = Vt + 8 * 4096 * 64;     // 4096*512
  (void)in_sizes; (void)n_in; (void)out_size; (void)ws_size;

  cvt_kernel<<<1424, 256, 0, stream>>>(x, Wq, Wk, Wv, Wo, xb, wqb, wkb, wvb, wob);
  qkv_kernel<<<dim3(64, 8, 3), 256, 0, stream>>>(xb, wqb, wkb, wvb, Qg, Kg, Vt);
  attn_kernel<<<dim3(64, 8), 256, 0, stream>>>(Qg, Kg, Vt, Hg);
  proj_kernel<<<64, 256, 0, stream>>>(Hg, wob, bo, out);
}